// Round 13
// baseline (408.087 us; speedup 1.0000x reference)
//
#include <hip/hip_runtime.h>
#include <hip/hip_bf16.h>

#define DEV __device__ __forceinline__

typedef __attribute__((ext_vector_type(8))) short bf16x8;
typedef __attribute__((ext_vector_type(4))) float f32x4;
typedef __attribute__((ext_vector_type(16))) float f32x16;
typedef __attribute__((ext_vector_type(4))) unsigned short u16x4;
typedef __attribute__((ext_vector_type(8))) unsigned short u16x8;

// ---- constants: B=2, L=2048, D=512, H=8, HD=64, NL=4 ----

DEV unsigned short f2bf(float f) {
  union { float f; unsigned u; } v; v.f = f;
  unsigned r = v.u + 0x7FFFu + ((v.u >> 16) & 1u);
  return (unsigned short)(r >> 16);
}

DEV float bf2f(unsigned short u) {
  union { unsigned u; float f; } v; v.u = ((unsigned)u) << 16; return v.f;
}

DEV void gload_lds16(const void* g, void* lds) {
  __builtin_amdgcn_global_load_lds(
      (const __attribute__((address_space(1))) unsigned int*)g,
      (__attribute__((address_space(3))) unsigned int*)lds, 16, 0, 0);
}

// byte offset into a [rows][64 bf16] (128B-row) tile with XOR swizzle
DEV int swz128(int r, int cb) { return r * 128 + (cb ^ ((r & 7) << 4)); }

// ---------------- fp32 -> bf16 weight convert ----------------
__global__ __launch_bounds__(256) void cvt_kernel(const float* __restrict__ s,
                                                  unsigned short* __restrict__ d, int n4) {
  int i = blockIdx.x * 256 + threadIdx.x;
  if (i >= n4) return;
  float4 v = ((const float4*)s)[i];
  u16x4 r; r[0] = f2bf(v.x); r[1] = f2bf(v.y); r[2] = f2bf(v.z); r[3] = f2bf(v.w);
  ((u16x4*)d)[i] = r;
}

// ---------------- per-row sum of bf16 weight matrix (K=512) ----------------
__global__ __launch_bounds__(256) void rowsum_kernel(const unsigned short* __restrict__ w,
                                                     float* __restrict__ rs) {
  int row = blockIdx.x * 4 + (threadIdx.x >> 6);
  int lane = threadIdx.x & 63;
  u16x8 v = *(const u16x8*)&w[(size_t)row * 512 + lane * 8];
  float s = 0.f;
#pragma unroll
  for (int e = 0; e < 8; ++e) s += bf2f(v[e]);
#pragma unroll
  for (int m = 1; m < 64; m <<= 1) s += __shfl_xor(s, m);
  if (lane == 0) rs[row] = s;
}

// ---------------- x = base + timing_signal ----------------
__global__ __launch_bounds__(256) void init_x_kernel(const float* __restrict__ base,
                                                     float* __restrict__ xf,
                                                     unsigned short* __restrict__ xb) {
  int i = blockIdx.x * 256 + threadIdx.x;          // 0 .. 2*2048*512-1
  int d = i & 511;
  int l = (i >> 9) & 2047;
  const float NEG_INC = -(float)(9.210340371976184 / 255.0);  // -ln(10000)/255
  int j = d & 255;
  float w = expf((float)j * NEG_INC);
  float ang = (float)(l - 1) * w;
  float ts = (d < 256) ? sinf(ang) : cosf(ang);
  float v = base[i] + ts;
  xf[i] = v;
  xb[i] = f2bf(v);
}

// reduce 512-slot partials -> per-batch affine (a, bi); every thread computes it
DEV void norm_affine(const float* pin, int batch, const float* nsc, const float* nbi,
                     int nlayer, int lane, float& a_in, float& bi_in) {
  const float* p = pin + batch * 1024;
  float s = 0.f, s2 = 0.f;
#pragma unroll
  for (int k = 0; k < 8; ++k) {
    int idx = lane + 64 * k;
    s += p[2 * idx];
    s2 += p[2 * idx + 1];
  }
#pragma unroll
  for (int m = 1; m < 64; m <<= 1) { s += __shfl_xor(s, m); s2 += __shfl_xor(s2, m); }
  const float invn = 1.f / 1048576.f;
  float mean = s * invn;
  float var = s2 * invn - mean * mean;
  float aa = nsc[nlayer] / sqrtf(var);
  a_in = aa;
  bi_in = nbi[nlayer] - mean * aa;
}

// ---------------- GEMM: C[M,N] = A[M,512] @ W[N,512]^T, norm folded ----------------
// x_norm = a*t + bi  =>  x_norm @ W^T = a*(t @ W^T) + bi*rowsum(W).
// MODE 0 (QKV): out bf16 = a*acc + bi*rs + bias (q-cols scaled log2e/8); fused V^T store.
// MODE 1 (f1):  A normed (attn out); v = acc + bias + (a*resid + bi); f32+bf16+partials.
// MODE 2 (f2):  v = relu(a*acc + bi*rs + bias) + (a*resid + bi); f32+bf16+partials.
// Tri-buffered LDS, counted vmcnt across raw s_barrier.
template<int MODE, int BM, int BN, int WR, int WC>
__global__ __launch_bounds__(WR * WC * 64) void gemm_kernel(
    const unsigned short* __restrict__ A,
    const unsigned short* __restrict__ W,
    const float* __restrict__ bias,
    const float* __restrict__ resid,
    unsigned short* __restrict__ outb,
    unsigned short* __restrict__ vtout,
    float* __restrict__ outf,
    float* __restrict__ partials,
    const float* __restrict__ pin,
    const float* __restrict__ nsc,
    const float* __restrict__ nbi,
    int nlayer,
    const float* __restrict__ rs,
    int N) {
  constexpr int T = WR * WC * 64;
  constexpr int WTM = BM / WR, WTN = BN / WC;
  constexpr int MR = WTM / 16, NR = WTN / 16;
  constexpr int IA = BM * 8 / T, IB = BN * 8 / T;
  static_assert(IA + IB == 6, "vmcnt immediate assumes 6 loads per stage");
  __shared__ __align__(16) unsigned short Al[3][BM * 64];
  __shared__ __align__(16) unsigned short Bl[3][BN * 64];
  __shared__ float red[WR * WC * 2];
  const int tid = threadIdx.x;
  const int lane = tid & 63, wid = tid >> 6;
  const int wr = wid / WC, wc = wid % WC;
  const int m0 = blockIdx.y * BM, n0 = blockIdx.x * BN;
  const int batch = m0 >> 11;

  // input-norm affine scalars (consume these loads fully before staging starts)
  float a_in = 1.f, bi_in = 0.f;
  if (pin) norm_affine(pin, batch, nsc, nbi, nlayer, lane, a_in, bi_in);
  asm volatile("s_waitcnt vmcnt(0)" ::: "memory");

  auto stage = [&](int kt, int buf) {
#pragma unroll
    for (int it = 0; it < IA; ++it) {
      int c = it * T + tid;
      int row = c >> 3, sub = c & 7;
      gload_lds16((const char*)A + (m0 + row) * 1024 + kt * 128 + sub * 16,
                  (char*)Al[buf] + (it * T + wid * 64) * 16);
    }
#pragma unroll
    for (int it = 0; it < IB; ++it) {
      int c = it * T + tid;
      int row = c >> 3, sub = c & 7;
      gload_lds16((const char*)W + (n0 + row) * 1024 + kt * 128 + sub * 16,
                  (char*)Bl[buf] + (it * T + wid * 64) * 16);
    }
  };

  f32x4 acc[MR][NR];
#pragma unroll
  for (int m = 0; m < MR; ++m)
#pragma unroll
    for (int n = 0; n < NR; ++n) acc[m][n] = (f32x4){0.f, 0.f, 0.f, 0.f};

  stage(0, 0);
  for (int kt = 0; kt < 8; ++kt) {
    int cur = kt % 3;
    if (kt < 7) {
      stage(kt + 1, (kt + 1) % 3);
      asm volatile("s_waitcnt vmcnt(6)" ::: "memory");
    } else {
      asm volatile("s_waitcnt vmcnt(0)" ::: "memory");
    }
    __builtin_amdgcn_s_barrier();
    asm volatile("" ::: "memory");
#pragma unroll
    for (int ks = 0; ks < 2; ++ks) {
      bf16x8 af[MR], bfr[NR];
#pragma unroll
      for (int m = 0; m < MR; ++m)
        af[m] = *(const bf16x8*)&Al[cur][(wr * WTM + m * 16 + (lane & 15)) * 64 + ks * 32 + (lane >> 4) * 8];
#pragma unroll
      for (int n = 0; n < NR; ++n)
        bfr[n] = *(const bf16x8*)&Bl[cur][(wc * WTN + n * 16 + (lane & 15)) * 64 + ks * 32 + (lane >> 4) * 8];
      __builtin_amdgcn_s_setprio(1);
#pragma unroll
      for (int m = 0; m < MR; ++m)
#pragma unroll
        for (int n = 0; n < NR; ++n)
          acc[m][n] = __builtin_amdgcn_mfma_f32_16x16x32_bf16(af[m], bfr[n], acc[m][n], 0, 0, 0);
      __builtin_amdgcn_s_setprio(0);
    }
  }

  float ps = 0.f, ps2 = 0.f;
#pragma unroll
  for (int m = 0; m < MR; ++m) {
    int row = m0 + wr * WTM + m * 16 + ((lane >> 4) << 2);
#pragma unroll
    for (int n = 0; n < NR; ++n) {
      int col = n0 + wc * WTN + n * 16 + (lane & 15);
      float bv = bias[col];
      float rsv = (MODE == 1) ? 0.f : rs[col];
      if (MODE == 0) {
        u16x4 q4;
#pragma unroll
        for (int j = 0; j < 4; ++j) {
          float v = a_in * acc[m][n][j] + bi_in * rsv + bv;
          if (col < 512) v *= 0.180336880f;  // fold (1/sqrt(HD)) * log2(e) into Q
          unsigned short bf = f2bf(v);
          q4[j] = bf;
          outb[(row + j) * N + col] = bf;
        }
        if (col >= 1024) {                   // fused V^T store: vT[b][h][d][l..l+3]
          int c2 = col - 1024;
          size_t va = ((size_t)((row >> 11) * 8 + (c2 >> 6)) * 64 + (c2 & 63)) * 2048 + (row & 2047);
          *(u16x4*)&vtout[va] = q4;
        }
      } else {
#pragma unroll
        for (int j = 0; j < 4; ++j) {
          int idx = (row + j) * N + col;
          float v;
          if (MODE == 1) {
            v = acc[m][n][j] + bv + (a_in * resid[idx] + bi_in);
          } else {
            v = fmaxf(a_in * acc[m][n][j] + bi_in * rsv + bv, 0.f) +
                (a_in * resid[idx] + bi_in);
          }
          outf[idx] = v;
          outb[idx] = f2bf(v);
          ps += v; ps2 += v * v;
        }
      }
    }
  }
  if (MODE != 0) {
#pragma unroll
    for (int s = 1; s < 64; s <<= 1) {
      ps += __shfl_xor(ps, s);
      ps2 += __shfl_xor(ps2, s);
    }
    if (lane == 0) { red[wid * 2] = ps; red[wid * 2 + 1] = ps2; }
    __syncthreads();
    if (tid == 0) {
      float s = 0.f, s2 = 0.f;
#pragma unroll
      for (int w = 0; w < WR * WC; ++w) { s += red[w * 2]; s2 += red[w * 2 + 1]; }
      constexpr int YPB = 2048 / BM;
      int slot = (blockIdx.y % YPB) * gridDim.x + blockIdx.x;   // 512 slots/batch
      partials[(batch * 512 + slot) * 2] = s;
      partials[(batch * 512 + slot) * 2 + 1] = s2;
    }
  }
}

// ---------------- flash attention: K in LDS (tri-buf), V direct global->reg ----------
// KV-split x4, grid 1024, LDS 24KB -> 3 blocks/CU (launch_bounds caps VGPR for 3 w/SIMD).
// V fragments are 16B/lane contiguous; issued right after barrier, consumed after
// softmax (~300cyc cover, L2-resident). K pipeline invariant: each iter's vf register
// wait (compiler-inserted, youngest vmem) retires the older K stage before the next
// barrier; prologue uses explicit vmcnt(0).
__global__ __launch_bounds__(256, 3) void attn_kernel(
    const unsigned short* __restrict__ qkv,   // [B,L,1536] bf16 (q pre-scaled log2e/8)
    const unsigned short* __restrict__ vT,    // [B,H,64,L] bf16
    unsigned short* __restrict__ op0,         // [32768][64] unnormalized O per split
    unsigned short* __restrict__ op1,
    unsigned short* __restrict__ op2,
    unsigned short* __restrict__ op3,
    float* __restrict__ ssums) {              // [4][32768]
  __shared__ __align__(16) unsigned short Kl[3][64 * 64];
  const int tid = threadIdx.x;
  const int lane = tid & 63, wid = tid >> 6;
  const int lq = lane & 31;
  const int g = lane >> 5;
  const int gx = g ^ 1;                      // PV K-dim permutation kv -> kv XOR 8
  // XCD swizzle: all 16 q-blocks of one (bh,sp) share lin%8 -> same XCD L2 (64%8==0)
  const int lin = blockIdx.x;                // 0..1023
  const int grp = lin & 63;
  const int xq = lin >> 6;                   // 0..15
  const int bh = grp >> 2, sp = grp & 3;
  const int b = bh >> 3, h = bh & 7;
  const int t0 = sp * 8;
  const int l0 = xq * 128;
  const int qrow = l0 + wid * 32 + lq;

  const size_t qoff = (size_t)b * 2048 * 1536 + h * 64;
  const size_t koff = qoff + 512;
  const unsigned short* vbase = vT + (size_t)(b * 8 + h) * 64 * 2048 + (size_t)lq * 2048 + gx * 8;

  bf16x8 qf[4];
#pragma unroll
  for (int dm = 0; dm < 4; ++dm)
    qf[dm] = *(const bf16x8*)&qkv[qoff + (size_t)qrow * 1536 + dm * 16 + g * 8];

  auto stageK = [&](int t, int buf) {
#pragma unroll
    for (int it = 0; it < 2; ++it) {
      int c = it * 256 + tid;
      int row = c >> 3, sub = c & 7;
      int sw = (sub * 16) ^ ((row & 7) << 4);
      gload_lds16((const char*)qkv + (koff + (size_t)(t * 64 + row) * 1536) * 2 + sw,
                  (char*)Kl[buf] + (it * 256 + wid * 64) * 16);
    }
  };

  union { unsigned short su[8]; bf16x8 v; } ou;
#pragma unroll
  for (int j = 0; j < 8; ++j) ou.su[j] = 0x3F80;
  const bf16x8 onesf = ou.v;

  f32x16 oacc[2], sacc;
#pragma unroll
  for (int i = 0; i < 16; ++i) { oacc[0][i] = 0.f; oacc[1][i] = 0.f; sacc[i] = 0.f; }

  auto pack2 = [&](const float* p, bf16x8& paA, bf16x8& paB) {
    unsigned w[8];
#pragma unroll
    for (int j = 0; j < 8; ++j)
      asm("v_cvt_pk_bf16_f32 %0, %1, %2" : "=v"(w[j]) : "v"(p[2 * j]), "v"(p[2 * j + 1]));
    asm("v_permlane32_swap_b32 %0, %1" : "+v"(w[0]), "+v"(w[2]));
    asm("v_permlane32_swap_b32 %0, %1" : "+v"(w[1]), "+v"(w[3]));
    asm("v_permlane32_swap_b32 %0, %1" : "+v"(w[4]), "+v"(w[6]));
    asm("v_permlane32_swap_b32 %0, %1" : "+v"(w[5]), "+v"(w[7]));
    union { unsigned u[4]; bf16x8 v; } a, c;
    a.u[0] = w[2]; a.u[1] = w[3]; a.u[2] = w[0]; a.u[3] = w[1];
    c.u[0] = w[6]; c.u[1] = w[7]; c.u[2] = w[4]; c.u[3] = w[5];
    paA = a.v; paB = c.v;
  };

  stageK(t0, 0);
  asm volatile("s_waitcnt vmcnt(0)" ::: "memory");
  for (int tt = 0; tt < 8; ++tt) {
    int cur = tt % 3;
    if (tt < 7) stageK(t0 + tt + 1, (tt + 1) % 3);
    __builtin_amdgcn_s_barrier();
    asm volatile("" ::: "memory");

    const int kv0 = (t0 + tt) * 64;
    // V fragments direct from global (issued early; consumed after softmax)
    bf16x8 vf[2][4];
#pragma unroll
    for (int dn = 0; dn < 2; ++dn)
#pragma unroll
      for (int q = 0; q < 4; ++q)
        vf[dn][q] = *(const bf16x8*)(vbase + (size_t)dn * 32 * 2048 + kv0 + q * 16);

    f32x16 s0, s1;
#pragma unroll
    for (int i = 0; i < 16; ++i) { s0[i] = 0.f; s1[i] = 0.f; }
#pragma unroll
    for (int dm = 0; dm < 4; ++dm) {
      bf16x8 kf0 = *(const bf16x8*)((const char*)Kl[cur] + swz128(lq, dm * 32 + g * 16));
      bf16x8 kf1 = *(const bf16x8*)((const char*)Kl[cur] + swz128(32 + lq, dm * 32 + g * 16));
      __builtin_amdgcn_s_setprio(1);
      s0 = __builtin_amdgcn_mfma_f32_32x32x16_bf16(kf0, qf[dm], s0, 0, 0, 0);
      s1 = __builtin_amdgcn_mfma_f32_32x32x16_bf16(kf1, qf[dm], s1, 0, 0, 0);
      __builtin_amdgcn_s_setprio(0);
    }

    float p0[16], p1[16];
#pragma unroll
    for (int i = 0; i < 16; ++i) {
      p0[i] = __builtin_amdgcn_exp2f(s0[i]);
      p1[i] = __builtin_amdgcn_exp2f(s1[i]);
    }

    bf16x8 fr[4];
    pack2(p0, fr[0], fr[1]);
    pack2(p1, fr[2], fr[3]);

    __builtin_amdgcn_s_setprio(1);
#pragma unroll
    for (int q = 0; q < 4; ++q)
      sacc = __builtin_amdgcn_mfma_f32_32x32x16_bf16(onesf, fr[q], sacc, 0, 0, 0);
#pragma unroll
    for (int dn = 0; dn < 2; ++dn)
#pragma unroll
      for (int q = 0; q < 4; ++q)
        oacc[dn] = __builtin_amdgcn_mfma_f32_32x32x16_bf16(vf[dn][q], fr[q], oacc[dn], 0, 0, 0);
    __builtin_amdgcn_s_setprio(0);
  }

  unsigned short* op = (sp == 0) ? op0 : (sp == 1) ? op1 : (sp == 2) ? op2 : op3;
  size_t obase = (size_t)bh * 131072;
#pragma unroll
  for (int dn = 0; dn < 2; ++dn)
#pragma unroll
    for (int ro = 0; ro < 4; ++ro) {
      int d0 = dn * 32 + ro * 8 + g * 4;
      u16x4 o4;
#pragma unroll
      for (int e = 0; e < 4; ++e) o4[e] = f2bf(oacc[dn][ro * 4 + e]);
      *(u16x4*)&op[obase + (size_t)qrow * 64 + d0] = o4;
    }
  if (lane < 32)
    ssums[(size_t)sp * 32768 + (size_t)bh * 2048 + qrow] = sacc[0];
}

// ---------------- combine the 4 KV-split partials ----------------
__global__ __launch_bounds__(256) void attn_combine_kernel(
    const unsigned short* __restrict__ op0,
    const unsigned short* __restrict__ op1,
    const unsigned short* __restrict__ op2,
    const unsigned short* __restrict__ op3,
    const float* __restrict__ ssums,           // [4][32768]
    unsigned short* __restrict__ o) {          // [B,L,512]
  const int tid = threadIdx.x;
  int row = blockIdx.x * 16 + (tid >> 4);
  int c0 = (tid & 15) * 4;
  float inv = 1.f / (ssums[row] + ssums[32768 + row] + ssums[65536 + row] + ssums[98304 + row]);
  u16x4 a0 = *(const u16x4*)&op0[(size_t)row * 64 + c0];
  u16x4 a1 = *(const u16x4*)&op1[(size_t)row * 64 + c0];
  u16x4 a2 = *(const u16x4*)&op2[(size_t)row * 64 + c0];
  u16x4 a3 = *(const u16x4*)&op3[(size_t)row * 64 + c0];
  int bh = row >> 11, l = row & 2047;
  int b = bh >> 3, h = bh & 7;
  u16x4 r;
#pragma unroll
  for (int e = 0; e < 4; ++e)
    r[e] = f2bf(((bf2f(a0[e]) + bf2f(a1[e])) + (bf2f(a2[e]) + bf2f(a3[e]))) * inv);
  *(u16x4*)&o[((size_t)(b * 2048 + l)) * 512 + h * 64 + c0] = r;
}

// ---------------- final output affine: d_out = a*t + bi ----------------
__global__ __launch_bounds__(256) void faffine_kernel(
    const float* __restrict__ in,
    const float* __restrict__ pin,
    const float* __restrict__ nsc,
    const float* __restrict__ nbi,
    int nlayer,
    float* __restrict__ out) {
  int i4 = blockIdx.x * 256 + threadIdx.x;
  size_t i = (size_t)i4 * 4;
  int batch = (int)(i >> 20);
  int lane = threadIdx.x & 63;
  float a, bi;
  norm_affine(pin, batch, nsc, nbi, nlayer, lane, a, bi);
  float4 v = *(const float4*)(in + i);
  float4 r;
  r.x = v.x * a + bi; r.y = v.y * a + bi; r.z = v.z * a + bi; r.w = v.w * a + bi;
  *(float4*)(out + i) = r;
}

extern "C" void kernel_launch(void* const* d_in, const int* in_sizes, int n_in,
                              void* d_out, int out_size, void* d_ws, size_t ws_size,
                              hipStream_t stream) {
  (void)in_sizes; (void)n_in; (void)out_size; (void)ws_size;
  const float* base  = (const float*)d_in[0];
  const float* qkv_w = (const float*)d_in[1];
  const float* qkv_b = (const float*)d_in[2];
  const float* f1_w  = (const float*)d_in[3];
  const float* f1_b  = (const float*)d_in[4];
  const float* f2_w  = (const float*)d_in[5];
  const float* f2_b  = (const float*)d_in[6];
  const float* n1s   = (const float*)d_in[7];
  const float* n1b   = (const float*)d_in[8];
  const float* n2s   = (const float*)d_in[9];
  const float* n2b   = (const float*)d_in[10];

  char* ws = (char*)d_ws;
  // region map (time-disjoint aliases noted):
  float*          t2_f32 = (float*)(ws + 0);                     // 0-8   raw t2 / layer-input f32
  unsigned short* t2_bf  = (unsigned short*)(ws + (8u << 20));   // 8-12  raw t2 bf16 (QKV A)
  unsigned short* op2    = (unsigned short*)(ws + (8u << 20));   // 8-12  attn partial (t2_bf dead
                                                                 //       between QKV-read & f2-write)
  unsigned short* qkv_bf = (unsigned short*)(ws + (12u << 20));  // 12-24 qkv (dead after attn)
  unsigned short* o_bf   = (unsigned short*)(ws + (12u << 20));  // 12-16 attn out (combine->f1)
  unsigned short* t1_bf  = (unsigned short*)(ws + (16u << 20));  // 16-20 raw t1 bf16 (f2 A)
  unsigned short* op3    = (unsigned short*)(ws + (24u << 20));  // 24-28 attn partial (free gap)
  unsigned short* vT     = (unsigned short*)(ws + (28u << 20));  // 28-32 V^T (dead before f1)
  float*          ssums  = (float*)(ws + (32u << 20));           // 32-32.5 (attn window only)
  float*          t1_f32 = (float*)(ws + (28u << 20));           // 28-36 raw t1 f32
  unsigned short* op0    = (unsigned short*)(ws + (36u << 20));  // 36-40 attn partial
  unsigned short* op1    = (unsigned short*)(ws + (40u << 20));  // 40-44 attn partial
  unsigned short* wq     = (unsigned short*)(ws + (44u << 20));  // 44-50 weights
  unsigned short* w1     = (unsigned short*)(ws + (50u << 20));  // 50-52
  unsigned short* w2     = (unsigned short*)(ws + (52u << 20));  // 52-54
  float*          parts1 = (float*)(ws + (54u << 20));           // 8 KB
  float*          parts2 = (float*)(ws + (54u << 20) + 16384);   // 8 KB
  float*          rsq    = (float*)(ws + (54u << 20) + 32768);   // 24 KB
  float*          rs2    = (float*)(ws + (54u << 20) + 65536);   // 8 KB

  cvt_kernel<<<3072, 256, 0, stream>>>(qkv_w, wq, 786432);
  cvt_kernel<<<1024, 256, 0, stream>>>(f1_w, w1, 262144);
  cvt_kernel<<<1024, 256, 0, stream>>>(f2_w, w2, 262144);
  rowsum_kernel<<<1536, 256, 0, stream>>>(wq, rsq);   // 4*1536 rows
  rowsum_kernel<<<512, 256, 0, stream>>>(w2, rs2);    // 4*512 rows
  init_x_kernel<<<8192, 256, 0, stream>>>(base, t2_f32, t2_bf);

  for (int L = 0; L < 4; ++L) {
    const float* pin_in = (L == 0) ? nullptr : parts2;   // norm2 of prev layer
    // QKV: A = bf16(t2_raw), input norm folded via (a,bi,rowsum)
    gemm_kernel<0, 64, 128, 1, 4><<<dim3(12, 64), 256, 0, stream>>>(
        t2_bf, wq + L * 786432, qkv_b + L * 1536, nullptr, qkv_bf, vT, nullptr,
        nullptr, pin_in, n2s, n2b, L - 1, rsq + L * 1536, 1536);
    attn_kernel<<<1024, 256, 0, stream>>>(qkv_bf, vT, op0, op1, op2, op3, ssums);
    attn_combine_kernel<<<2048, 256, 0, stream>>>(op0, op1, op2, op3, ssums, o_bf);
    // f1: A = o (normed by softmax), resid = a*t2_raw + bi
    gemm_kernel<1, 32, 64, 1, 2><<<dim3(8, 128), 128, 0, stream>>>(
        o_bf, w1 + L * 262144, f1_b + L * 512, t2_f32, t1_bf, nullptr, t1_f32,
        parts1, pin_in, n2s, n2b, L - 1, nullptr, 512);
    // f2: A = bf16(t1_raw) with norm1 folded; resid = a1*t1_raw + bi1
    gemm_kernel<2, 32, 64, 1, 2><<<dim3(8, 128), 128, 0, stream>>>(
        t1_bf, w2 + L * 262144, f2_b + L * 512, t1_f32, t2_bf, nullptr, t2_f32,
        parts2, parts1, n1s, n1b, L, rs2 + L * 512, 512);
  }
  faffine_kernel<<<2048, 256, 0, stream>>>(t2_f32, parts2, n2s, n2b, 3, (float*)d_out);
}

// Round 14
// 323.188 us; speedup vs baseline: 1.2627x; 1.2627x over previous
//
#include <hip/hip_runtime.h>
#include <hip/hip_bf16.h>

#define DEV __device__ __forceinline__

typedef __attribute__((ext_vector_type(8))) short bf16x8;
typedef __attribute__((ext_vector_type(4))) float f32x4;
typedef __attribute__((ext_vector_type(16))) float f32x16;
typedef __attribute__((ext_vector_type(4))) unsigned short u16x4;
typedef __attribute__((ext_vector_type(8))) unsigned short u16x8;

// ---- constants: B=2, L=2048, D=512, H=8, HD=64, NL=4 ----

DEV unsigned short f2bf(float f) {
  union { float f; unsigned u; } v; v.f = f;
  unsigned r = v.u + 0x7FFFu + ((v.u >> 16) & 1u);
  return (unsigned short)(r >> 16);
}

DEV float bf2f(unsigned short u) {
  union { unsigned u; float f; } v; v.u = ((unsigned)u) << 16; return v.f;
}

DEV void gload_lds16(const void* g, void* lds) {
  __builtin_amdgcn_global_load_lds(
      (const __attribute__((address_space(1))) unsigned int*)g,
      (__attribute__((address_space(3))) unsigned int*)lds, 16, 0, 0);
}

// byte offset into a [rows][64 bf16] (128B-row) tile with XOR swizzle
DEV int swz128(int r, int cb) { return r * 128 + (cb ^ ((r & 7) << 4)); }

// ---------------- fp32 -> bf16 weight convert + fused per-row sum ----------------
// One 256-thread block covers exactly 2 rows (512 cols) of a weight matrix.
// Row sums are computed from the ROUNDED bf16 values (identical to what the GEMM
// consumes), written to rs[2*bid], rs[2*bid+1] when rs != null.
__global__ __launch_bounds__(256) void cvt_kernel(const float* __restrict__ s,
                                                  unsigned short* __restrict__ d,
                                                  float* __restrict__ rs, int n4) {
  __shared__ float red[4];
  int i = blockIdx.x * 256 + threadIdx.x;
  if (i >= n4) return;
  float4 v = ((const float4*)s)[i];
  u16x4 r; r[0] = f2bf(v.x); r[1] = f2bf(v.y); r[2] = f2bf(v.z); r[3] = f2bf(v.w);
  ((u16x4*)d)[i] = r;
  if (rs) {
    float ls = bf2f(r[0]) + bf2f(r[1]) + bf2f(r[2]) + bf2f(r[3]);
#pragma unroll
    for (int m = 1; m < 64; m <<= 1) ls += __shfl_xor(ls, m);
    int wid = threadIdx.x >> 6;
    if ((threadIdx.x & 63) == 0) red[wid] = ls;
    __syncthreads();
    if (threadIdx.x == 0) rs[blockIdx.x * 2] = red[0] + red[1];
    if (threadIdx.x == 128) rs[blockIdx.x * 2 + 1] = red[2] + red[3];
  }
}

// ---------------- x = base + timing_signal ----------------
__global__ __launch_bounds__(256) void init_x_kernel(const float* __restrict__ base,
                                                     float* __restrict__ xf,
                                                     unsigned short* __restrict__ xb) {
  int i = blockIdx.x * 256 + threadIdx.x;          // 0 .. 2*2048*512-1
  int d = i & 511;
  int l = (i >> 9) & 2047;
  const float NEG_INC = -(float)(9.210340371976184 / 255.0);  // -ln(10000)/255
  int j = d & 255;
  float w = expf((float)j * NEG_INC);
  float ang = (float)(l - 1) * w;
  float ts = (d < 256) ? sinf(ang) : cosf(ang);
  float v = base[i] + ts;
  xf[i] = v;
  xb[i] = f2bf(v);
}

// reduce 512-slot partials -> per-batch affine (a, bi); every thread computes it
DEV void norm_affine(const float* pin, int batch, const float* nsc, const float* nbi,
                     int nlayer, int lane, float& a_in, float& bi_in) {
  const float* p = pin + batch * 1024;
  float s = 0.f, s2 = 0.f;
#pragma unroll
  for (int k = 0; k < 8; ++k) {
    int idx = lane + 64 * k;
    s += p[2 * idx];
    s2 += p[2 * idx + 1];
  }
#pragma unroll
  for (int m = 1; m < 64; m <<= 1) { s += __shfl_xor(s, m); s2 += __shfl_xor(s2, m); }
  const float invn = 1.f / 1048576.f;
  float mean = s * invn;
  float var = s2 * invn - mean * mean;
  float aa = nsc[nlayer] / sqrtf(var);
  a_in = aa;
  bi_in = nbi[nlayer] - mean * aa;
}

// ---------------- GEMM: C[M,N] = A[M,512] @ W[N,512]^T, norm folded ----------------
// x_norm = a*t + bi  =>  x_norm @ W^T = a*(t @ W^T) + bi*rowsum(W).
// MODE 0 (QKV): out bf16 = a*acc + bi*rs + bias (q-cols scaled log2e/8); fused V^T store.
// MODE 1 (f1):  A normed (attn out); v = acc + bias + (a*resid + bi); f32+bf16+partials.
// MODE 2 (f2):  v = relu(a*acc + bi*rs + bias) + (a*resid + bi); f32+bf16+partials.
// Tri-buffered LDS, counted vmcnt across raw s_barrier.
template<int MODE, int BM, int BN, int WR, int WC>
__global__ __launch_bounds__(WR * WC * 64) void gemm_kernel(
    const unsigned short* __restrict__ A,
    const unsigned short* __restrict__ W,
    const float* __restrict__ bias,
    const float* __restrict__ resid,
    unsigned short* __restrict__ outb,
    unsigned short* __restrict__ vtout,
    float* __restrict__ outf,
    float* __restrict__ partials,
    const float* __restrict__ pin,
    const float* __restrict__ nsc,
    const float* __restrict__ nbi,
    int nlayer,
    const float* __restrict__ rs,
    int N) {
  constexpr int T = WR * WC * 64;
  constexpr int WTM = BM / WR, WTN = BN / WC;
  constexpr int MR = WTM / 16, NR = WTN / 16;
  constexpr int IA = BM * 8 / T, IB = BN * 8 / T;
  static_assert(IA + IB == 6, "vmcnt immediate assumes 6 loads per stage");
  __shared__ __align__(16) unsigned short Al[3][BM * 64];
  __shared__ __align__(16) unsigned short Bl[3][BN * 64];
  __shared__ float red[WR * WC * 2];
  const int tid = threadIdx.x;
  const int lane = tid & 63, wid = tid >> 6;
  const int wr = wid / WC, wc = wid % WC;
  const int m0 = blockIdx.y * BM, n0 = blockIdx.x * BN;
  const int batch = m0 >> 11;

  // input-norm affine scalars (consume these loads fully before staging starts)
  float a_in = 1.f, bi_in = 0.f;
  if (pin) norm_affine(pin, batch, nsc, nbi, nlayer, lane, a_in, bi_in);
  asm volatile("s_waitcnt vmcnt(0)" ::: "memory");

  auto stage = [&](int kt, int buf) {
#pragma unroll
    for (int it = 0; it < IA; ++it) {
      int c = it * T + tid;
      int row = c >> 3, sub = c & 7;
      gload_lds16((const char*)A + (m0 + row) * 1024 + kt * 128 + sub * 16,
                  (char*)Al[buf] + (it * T + wid * 64) * 16);
    }
#pragma unroll
    for (int it = 0; it < IB; ++it) {
      int c = it * T + tid;
      int row = c >> 3, sub = c & 7;
      gload_lds16((const char*)W + (n0 + row) * 1024 + kt * 128 + sub * 16,
                  (char*)Bl[buf] + (it * T + wid * 64) * 16);
    }
  };

  f32x4 acc[MR][NR];
#pragma unroll
  for (int m = 0; m < MR; ++m)
#pragma unroll
    for (int n = 0; n < NR; ++n) acc[m][n] = (f32x4){0.f, 0.f, 0.f, 0.f};

  stage(0, 0);
  for (int kt = 0; kt < 8; ++kt) {
    int cur = kt % 3;
    if (kt < 7) {
      stage(kt + 1, (kt + 1) % 3);
      asm volatile("s_waitcnt vmcnt(6)" ::: "memory");
    } else {
      asm volatile("s_waitcnt vmcnt(0)" ::: "memory");
    }
    __builtin_amdgcn_s_barrier();
    asm volatile("" ::: "memory");
#pragma unroll
    for (int ks = 0; ks < 2; ++ks) {
      bf16x8 af[MR], bfr[NR];
#pragma unroll
      for (int m = 0; m < MR; ++m)
        af[m] = *(const bf16x8*)&Al[cur][(wr * WTM + m * 16 + (lane & 15)) * 64 + ks * 32 + (lane >> 4) * 8];
#pragma unroll
      for (int n = 0; n < NR; ++n)
        bfr[n] = *(const bf16x8*)&Bl[cur][(wc * WTN + n * 16 + (lane & 15)) * 64 + ks * 32 + (lane >> 4) * 8];
      __builtin_amdgcn_s_setprio(1);
#pragma unroll
      for (int m = 0; m < MR; ++m)
#pragma unroll
        for (int n = 0; n < NR; ++n)
          acc[m][n] = __builtin_amdgcn_mfma_f32_16x16x32_bf16(af[m], bfr[n], acc[m][n], 0, 0, 0);
      __builtin_amdgcn_s_setprio(0);
    }
  }

  float ps = 0.f, ps2 = 0.f;
#pragma unroll
  for (int m = 0; m < MR; ++m) {
    int row = m0 + wr * WTM + m * 16 + ((lane >> 4) << 2);
#pragma unroll
    for (int n = 0; n < NR; ++n) {
      int col = n0 + wc * WTN + n * 16 + (lane & 15);
      float bv = bias[col];
      float rsv = (MODE == 1) ? 0.f : rs[col];
      if (MODE == 0) {
        u16x4 q4;
#pragma unroll
        for (int j = 0; j < 4; ++j) {
          float v = a_in * acc[m][n][j] + bi_in * rsv + bv;
          if (col < 512) v *= 0.180336880f;  // fold (1/sqrt(HD)) * log2(e) into Q
          unsigned short bf = f2bf(v);
          q4[j] = bf;
          outb[(row + j) * N + col] = bf;
        }
        if (col >= 1024) {                   // fused V^T store: vT[b][h][d][l..l+3]
          int c2 = col - 1024;
          size_t va = ((size_t)((row >> 11) * 8 + (c2 >> 6)) * 64 + (c2 & 63)) * 2048 + (row & 2047);
          *(u16x4*)&vtout[va] = q4;
        }
      } else {
#pragma unroll
        for (int j = 0; j < 4; ++j) {
          int idx = (row + j) * N + col;
          float v;
          if (MODE == 1) {
            v = acc[m][n][j] + bv + (a_in * resid[idx] + bi_in);
          } else {
            v = fmaxf(a_in * acc[m][n][j] + bi_in * rsv + bv, 0.f) +
                (a_in * resid[idx] + bi_in);
          }
          outf[idx] = v;
          outb[idx] = f2bf(v);
          ps += v; ps2 += v * v;
        }
      }
    }
  }
  if (MODE != 0) {
#pragma unroll
    for (int s = 1; s < 64; s <<= 1) {
      ps += __shfl_xor(ps, s);
      ps2 += __shfl_xor(ps2, s);
    }
    if (lane == 0) { red[wid * 2] = ps; red[wid * 2 + 1] = ps2; }
    __syncthreads();
    if (tid == 0) {
      float s = 0.f, s2 = 0.f;
#pragma unroll
      for (int w = 0; w < WR * WC; ++w) { s += red[w * 2]; s2 += red[w * 2 + 1]; }
      constexpr int YPB = 2048 / BM;
      int slot = (blockIdx.y % YPB) * gridDim.x + blockIdx.x;   // 512 slots/batch
      partials[(batch * 512 + slot) * 2] = s;
      partials[(batch * 512 + slot) * 2 + 1] = s2;
    }
  }
}

// ---------------- flash attention (round-10 proven config) ----------------
// KV-split x2, XCD swizzle, K+V LDS tri-buffer, counted vmcnt across raw s_barrier.
__global__ __launch_bounds__(256) void attn_kernel(
    const unsigned short* __restrict__ qkv,   // [B,L,1536] bf16 (q pre-scaled log2e/8)
    const unsigned short* __restrict__ vT,    // [B,H,64,L] bf16
    unsigned short* __restrict__ op0,         // [32768][64] unnormalized O, split 0
    unsigned short* __restrict__ op1,         // split 1
    float* __restrict__ ssums) {              // [2][32768]
  __shared__ __align__(16) unsigned short Kl[3][64 * 64];
  __shared__ __align__(16) unsigned short Vl[3][64 * 64];
  const int tid = threadIdx.x;
  const int lane = tid & 63, wid = tid >> 6;
  const int lq = lane & 31;
  const int g = lane >> 5;
  // XCD swizzle: all 16 q-blocks of one (bh,sp) share lin%8 -> same XCD L2
  const int lin = blockIdx.x;                // 0..511
  const int xq = (lin >> 3) & 15;
  const int pair = (lin & 7) + 8 * (lin >> 7);   // 0..31
  const int bh = pair >> 1, sp = pair & 1;
  const int b = bh >> 3, h = bh & 7;
  const int l0 = xq * 128;
  const int qrow = l0 + wid * 32 + lq;

  const size_t qoff = (size_t)b * 2048 * 1536 + h * 64;
  const size_t koff = qoff + 512;
  const size_t voff = (size_t)(b * 8 + h) * 64 * 2048;

  bf16x8 qf[4];
#pragma unroll
  for (int dm = 0; dm < 4; ++dm)
    qf[dm] = *(const bf16x8*)&qkv[qoff + (size_t)qrow * 1536 + dm * 16 + g * 8];

  auto stageKV = [&](int t, int buf) {
#pragma unroll
    for (int it = 0; it < 2; ++it) {
      int c = it * 256 + tid;
      int row = c >> 3, sub = c & 7;
      int sw = (sub * 16) ^ ((row & 7) << 4);
      gload_lds16((const char*)qkv + (koff + (size_t)(t * 64 + row) * 1536) * 2 + sw,
                  (char*)Kl[buf] + (it * 256 + wid * 64) * 16);
    }
#pragma unroll
    for (int it = 0; it < 2; ++it) {
      int c = it * 256 + tid;
      int row = c >> 3, sub = c & 7;
      int sw = (sub * 16) ^ ((row & 7) << 4);
      gload_lds16((const char*)vT + (voff + (size_t)row * 2048 + t * 64) * 2 + sw,
                  (char*)Vl[buf] + (it * 256 + wid * 64) * 16);
    }
  };

  union { unsigned short su[8]; bf16x8 v; } ou;
#pragma unroll
  for (int j = 0; j < 8; ++j) ou.su[j] = 0x3F80;
  const bf16x8 onesf = ou.v;

  f32x16 oacc[2], sacc;
#pragma unroll
  for (int i = 0; i < 16; ++i) { oacc[0][i] = 0.f; oacc[1][i] = 0.f; sacc[i] = 0.f; }

  auto pack2 = [&](const float* p, bf16x8& paA, bf16x8& paB) {
    unsigned w[8];
#pragma unroll
    for (int j = 0; j < 8; ++j)
      asm("v_cvt_pk_bf16_f32 %0, %1, %2" : "=v"(w[j]) : "v"(p[2 * j]), "v"(p[2 * j + 1]));
    asm("v_permlane32_swap_b32 %0, %1" : "+v"(w[0]), "+v"(w[2]));
    asm("v_permlane32_swap_b32 %0, %1" : "+v"(w[1]), "+v"(w[3]));
    asm("v_permlane32_swap_b32 %0, %1" : "+v"(w[4]), "+v"(w[6]));
    asm("v_permlane32_swap_b32 %0, %1" : "+v"(w[5]), "+v"(w[7]));
    union { unsigned u[4]; bf16x8 v; } a, c;
    a.u[0] = w[2]; a.u[1] = w[3]; a.u[2] = w[0]; a.u[3] = w[1];
    c.u[0] = w[6]; c.u[1] = w[7]; c.u[2] = w[4]; c.u[3] = w[5];
    paA = a.v; paB = c.v;
  };

  stageKV(sp * 16, 0);
  for (int tt = 0; tt < 16; ++tt) {
    int cur = tt % 3;
    if (tt < 15) {
      stageKV(sp * 16 + tt + 1, (tt + 1) % 3);
      asm volatile("s_waitcnt vmcnt(4)" ::: "memory");
    } else {
      asm volatile("s_waitcnt vmcnt(0)" ::: "memory");
    }
    __builtin_amdgcn_s_barrier();
    asm volatile("" ::: "memory");

    f32x16 s0, s1;
#pragma unroll
    for (int i = 0; i < 16; ++i) { s0[i] = 0.f; s1[i] = 0.f; }
#pragma unroll
    for (int dm = 0; dm < 4; ++dm) {
      bf16x8 kf0 = *(const bf16x8*)((const char*)Kl[cur] + swz128(lq, dm * 32 + g * 16));
      bf16x8 kf1 = *(const bf16x8*)((const char*)Kl[cur] + swz128(32 + lq, dm * 32 + g * 16));
      __builtin_amdgcn_s_setprio(1);
      s0 = __builtin_amdgcn_mfma_f32_32x32x16_bf16(kf0, qf[dm], s0, 0, 0, 0);
      s1 = __builtin_amdgcn_mfma_f32_32x32x16_bf16(kf1, qf[dm], s1, 0, 0, 0);
      __builtin_amdgcn_s_setprio(0);
    }

    float p0[16], p1[16];
#pragma unroll
    for (int i = 0; i < 16; ++i) {
      p0[i] = __builtin_amdgcn_exp2f(s0[i]);
      p1[i] = __builtin_amdgcn_exp2f(s1[i]);
    }

    bf16x8 fr[4];
    pack2(p0, fr[0], fr[1]);
    pack2(p1, fr[2], fr[3]);

    __builtin_amdgcn_s_setprio(1);
#pragma unroll
    for (int q = 0; q < 4; ++q)
      sacc = __builtin_amdgcn_mfma_f32_32x32x16_bf16(onesf, fr[q], sacc, 0, 0, 0);
    __builtin_amdgcn_s_setprio(0);

#pragma unroll
    for (int dn = 0; dn < 2; ++dn) {
      bf16x8 vf[4];
#pragma unroll
      for (int q = 0; q < 4; ++q)
        vf[q] = *(const bf16x8*)((const char*)Vl[cur] +
                                 swz128(dn * 32 + lq, q * 32 + (g ^ 1) * 16));
      __builtin_amdgcn_s_setprio(1);
#pragma unroll
      for (int q = 0; q < 4; ++q)
        oacc[dn] = __builtin_amdgcn_mfma_f32_32x32x16_bf16(vf[q], fr[q], oacc[dn], 0, 0, 0);
      __builtin_amdgcn_s_setprio(0);
    }
  }

  unsigned short* op = sp ? op1 : op0;
  size_t obase = (size_t)bh * 131072;
#pragma unroll
  for (int dn = 0; dn < 2; ++dn)
#pragma unroll
    for (int ro = 0; ro < 4; ++ro) {
      int d0 = dn * 32 + ro * 8 + g * 4;
      u16x4 o4;
#pragma unroll
      for (int e = 0; e < 4; ++e) o4[e] = f2bf(oacc[dn][ro * 4 + e]);
      *(u16x4*)&op[obase + (size_t)qrow * 64 + d0] = o4;
    }
  if (lane < 32)
    ssums[(size_t)sp * 32768 + (size_t)bh * 2048 + qrow] = sacc[0];
}

// ---------------- combine the 2 KV-split partials ----------------
__global__ __launch_bounds__(256) void attn_combine_kernel(
    const unsigned short* __restrict__ op0,
    const unsigned short* __restrict__ op1,
    const float* __restrict__ ssums,
    unsigned short* __restrict__ o) {          // [B,L,512]
  const int tid = threadIdx.x;
  int row = blockIdx.x * 16 + (tid >> 4);
  int c0 = (tid & 15) * 4;
  float inv = 1.f / (ssums[row] + ssums[32768 + row]);
  u16x4 a0 = *(const u16x4*)&op0[(size_t)row * 64 + c0];
  u16x4 a1 = *(const u16x4*)&op1[(size_t)row * 64 + c0];
  int bh = row >> 11, l = row & 2047;
  int b = bh >> 3, h = bh & 7;
  u16x4 r;
#pragma unroll
  for (int e = 0; e < 4; ++e)
    r[e] = f2bf((bf2f(a0[e]) + bf2f(a1[e])) * inv);
  *(u16x4*)&o[((size_t)(b * 2048 + l)) * 512 + h * 64 + c0] = r;
}

// ---------------- final output affine: d_out = a*t + bi ----------------
__global__ __launch_bounds__(256) void faffine_kernel(
    const float* __restrict__ in,
    const float* __restrict__ pin,
    const float* __restrict__ nsc,
    const float* __restrict__ nbi,
    int nlayer,
    float* __restrict__ out) {
  int i4 = blockIdx.x * 256 + threadIdx.x;
  size_t i = (size_t)i4 * 4;
  int batch = (int)(i >> 20);
  int lane = threadIdx.x & 63;
  float a, bi;
  norm_affine(pin, batch, nsc, nbi, nlayer, lane, a, bi);
  float4 v = *(const float4*)(in + i);
  float4 r;
  r.x = v.x * a + bi; r.y = v.y * a + bi; r.z = v.z * a + bi; r.w = v.w * a + bi;
  *(float4*)(out + i) = r;
}

extern "C" void kernel_launch(void* const* d_in, const int* in_sizes, int n_in,
                              void* d_out, int out_size, void* d_ws, size_t ws_size,
                              hipStream_t stream) {
  (void)in_sizes; (void)n_in; (void)out_size; (void)ws_size;
  const float* base  = (const float*)d_in[0];
  const float* qkv_w = (const float*)d_in[1];
  const float* qkv_b = (const float*)d_in[2];
  const float* f1_w  = (const float*)d_in[3];
  const float* f1_b  = (const float*)d_in[4];
  const float* f2_w  = (const float*)d_in[5];
  const float* f2_b  = (const float*)d_in[6];
  const float* n1s   = (const float*)d_in[7];
  const float* n1b   = (const float*)d_in[8];
  const float* n2s   = (const float*)d_in[9];
  const float* n2b   = (const float*)d_in[10];

  char* ws = (char*)d_ws;
  // region map (time-disjoint aliases noted):
  float*          t2_f32 = (float*)(ws + 0);                     // 0-8   raw t2 / layer-input f32
  unsigned short* t2_bf  = (unsigned short*)(ws + (8u << 20));   // 8-12  raw t2 bf16 (QKV A)
  unsigned short* qkv_bf = (unsigned short*)(ws + (12u << 20));  // 12-24 qkv (dead after attn)
  unsigned short* o_bf   = (unsigned short*)(ws + (12u << 20));  // 12-16 attn out (combine->f1)
  unsigned short* t1_bf  = (unsigned short*)(ws + (16u << 20));  // 16-20 raw t1 bf16 (f2 A)
  unsigned short* vT     = (unsigned short*)(ws + (28u << 20));  // 28-32 V^T (dead before f1)
  float*          ssums  = (float*)(ws + (32u << 20));           // 32-32.25 (attn window only)
  float*          t1_f32 = (float*)(ws + (28u << 20));           // 28-36 raw t1 f32
  unsigned short* op0    = (unsigned short*)(ws + (36u << 20));  // 36-40 attn partial
  unsigned short* op1    = (unsigned short*)(ws + (40u << 20));  // 40-44 attn partial
  unsigned short* wq     = (unsigned short*)(ws + (44u << 20));  // 44-50 weights
  unsigned short* w1     = (unsigned short*)(ws + (50u << 20));  // 50-52
  unsigned short* w2     = (unsigned short*)(ws + (52u << 20));  // 52-54
  float*          parts1 = (float*)(ws + (54u << 20));           // 8 KB
  float*          parts2 = (float*)(ws + (54u << 20) + 16384);   // 8 KB
  float*          rsq    = (float*)(ws + (54u << 20) + 32768);   // 24 KB
  float*          rs2    = (float*)(ws + (54u << 20) + 65536);   // 8 KB

  cvt_kernel<<<3072, 256, 0, stream>>>(qkv_w, wq, rsq, 786432);   // + fused rowsum
  cvt_kernel<<<1024, 256, 0, stream>>>(f1_w, w1, nullptr, 262144);
  cvt_kernel<<<1024, 256, 0, stream>>>(f2_w, w2, rs2, 262144);    // + fused rowsum
  init_x_kernel<<<8192, 256, 0, stream>>>(base, t2_f32, t2_bf);

  for (int L = 0; L < 4; ++L) {
    const float* pin_in = (L == 0) ? nullptr : parts2;   // norm2 of prev layer
    // QKV: A = bf16(t2_raw), input norm folded via (a,bi,rowsum)
    gemm_kernel<0, 64, 128, 1, 4><<<dim3(12, 64), 256, 0, stream>>>(
        t2_bf, wq + L * 786432, qkv_b + L * 1536, nullptr, qkv_bf, vT, nullptr,
        nullptr, pin_in, n2s, n2b, L - 1, rsq + L * 1536, 1536);
    attn_kernel<<<512, 256, 0, stream>>>(qkv_bf, vT, op0, op1, ssums);
    attn_combine_kernel<<<2048, 256, 0, stream>>>(op0, op1, ssums, o_bf);
    // f1: A = o (normed by softmax), resid = a*t2_raw + bi
    gemm_kernel<1, 32, 64, 1, 2><<<dim3(8, 128), 128, 0, stream>>>(
        o_bf, w1 + L * 262144, f1_b + L * 512, t2_f32, t1_bf, nullptr, t1_f32,
        parts1, pin_in, n2s, n2b, L - 1, nullptr, 512);
    // f2: A = bf16(t1_raw) with norm1 folded; resid = a1*t1_raw + bi1
    gemm_kernel<2, 32, 64, 1, 2><<<dim3(8, 128), 128, 0, stream>>>(
        t1_bf, w2 + L * 262144, f2_b + L * 512, t1_f32, t2_bf, nullptr, t2_f32,
        parts2, parts1, n1s, n1b, L, rs2 + L * 512, 512);
  }
  faffine_kernel<<<2048, 256, 0, stream>>>(t2_f32, parts2, n2s, n2b, 3, (float*)d_out);
}